// Round 13
// baseline (85.455 us; speedup 1.0000x reference)
//
#include <hip/hip_runtime.h>

// ---------------------------------------------------------------------------
// TreeEncoder fused MFMA kernel, round 13 = round 12 + amdgpu_num_vgpr(128).
//   r12's persistent-weight producer/consumer was compiled with VGPR=64
//   (launch_bounds(1024) heuristic targeted 2 blocks/CU) -> the 48-VGPR
//   persistent BUF spilled to scratch (WRITE 28MB), voiding the design.
//   A 1024-thread block is 16 waves = 4/SIMD solo -> budget is exactly
//   512/4 = 128 VGPR.  Pin it (r7->r8 precedent: the exact-cap attribute
//   gives exactly 128 with no catastrophic spill).
//   Design recap:
//   - grid 256 x 1024 (1 block/CU, block == batch; no atomics, no memset).
//   - wave w permanently holds the 12 B-fragments of (layer=w>>3, t=w&7)
//     in 48 VGPRs; the per-step L2 weight stream vanishes from the loop.
//   - rows stream in 16 tiles of 32; beat j: L0-waves h0(j)->h1(j);
//     L1-waves h1(j-1)->msum and embed tile j+1.  Double-buffered LDS,
//     ONE __syncthreads per beat, 17 beats.
// ---------------------------------------------------------------------------

typedef short bf16x8 __attribute__((ext_vector_type(8)));
typedef float f32x4  __attribute__((ext_vector_type(4)));

#define MFMA16(a, b, c) __builtin_amdgcn_mfma_f32_16x16x32_bf16((a), (b), (c), 0, 0, 0)

#define NEG_L2E (-1.44269504088896f)
#define TWO_L2E (2.88539008177793f)

__device__ __forceinline__ unsigned short f2bf(float f) {
    return (unsigned short)((__float_as_uint(f) + 0x8000u) >> 16);
}
__device__ __forceinline__ float frcp(float x)  { return __builtin_amdgcn_rcpf(x); }
__device__ __forceinline__ float fexp2(float x) { return __builtin_amdgcn_exp2f(x); }

// scalar Pade[3/2] merged activation: inputs are pre-scaled logits
__device__ __forceinline__ float act_h(float iv, float ov, float cv) {
    float ei = fexp2(iv);
    float eo = fexp2(ov);
    float u  = fexp2(cv);
    float p  = u - 1.0f;
    float q  = (1.0f + ei) * (u + 1.0f);     // cc = p/q = sig(i)*tanh(c~)
    float p2 = p * p, q2 = q * q;
    float t15 = 15.0f * q2;
    return (p * (t15 + p2)) * frcp((q * (6.0f * p2 + t15)) * (1.0f + eo));
}

__device__ __forceinline__ bf16x8 pack8(float4 v0, float4 v1) {
    bf16x8 a;
    a[0] = (short)f2bf(v0.x); a[1] = (short)f2bf(v0.y);
    a[2] = (short)f2bf(v0.z); a[3] = (short)f2bf(v0.w);
    a[4] = (short)f2bf(v1.x); a[5] = (short)f2bf(v1.y);
    a[6] = (short)f2bf(v1.z); a[7] = (short)f2bf(v1.w);
    return a;
}

// ---------------------------------------------------------------------------
// Prep: weights -> MFMA B-fragment bf16 layout in ws, with exp2 prescale;
// plus combined scaled biases.  (identical to rounds 8-12)
// ---------------------------------------------------------------------------
__global__ void prep_frags(const float* __restrict__ embW,
                           const float* __restrict__ Wi,
                           const float* __restrict__ Wo,
                           const float* __restrict__ Wc,
                           const float* __restrict__ bWi, const float* __restrict__ bUi,
                           const float* __restrict__ bWo, const float* __restrict__ bUo,
                           const float* __restrict__ bWc, const float* __restrict__ bUc,
                           char* __restrict__ ws) {
    int fb = blockIdx.x;          // 0..208
    int l  = threadIdx.x;         // 0..63

    if (fb == 208) {              // combined scaled biases: [layer][gate][128]
        float* bias = reinterpret_cast<float*>(ws + 212992);
#pragma unroll
        for (int j = 0; j < 12; ++j) {
            int v = j * 64 + l;                 // 0..767
            int layer = v / 384;
            int r = v % 384;
            int gate = r >> 7;
            int c = r & 127;
            int idx = layer * 128 + c;
            float x;
            if (gate == 0)      x = NEG_L2E * (bWi[idx] + bUi[idx]);
            else if (gate == 1) x = NEG_L2E * (bWo[idx] + bUo[idx]);
            else                x = TWO_L2E * (bWc[idx] + bUc[idx]);
            bias[v] = x;
        }
        return;
    }

    int g  = l >> 4, c0 = l & 15;
    const float* src;
    int t, kk;
    size_t dst;
    float scale;
    if (fb < 16) {
        t = fb >> 1; kk = fb & 1;
        src = embW;                                   // [64][128]
        dst = (size_t)fb * 1024;
        scale = 1.0f;
    } else {
        int r = fb - 16;                              // (layer*8+t)*12+gate*4+kk
        int layer = r / 96;
        int r2 = r % 96;
        t = r2 / 12;
        int r3 = r2 % 12;
        int gate = r3 >> 2;
        kk = r3 & 3;
        const float* Ws[3] = {Wi, Wo, Wc};
        src = Ws[gate] + (size_t)layer * 128 * 128;   // [128][128]
        dst = 16384 + (size_t)r * 1024;
        scale = (gate == 2) ? TWO_L2E : NEG_L2E;
    }

    bf16x8 v;
#pragma unroll
    for (int e = 0; e < 8; ++e) {
        int k   = kk * 32 + g * 8 + e;
        int col = t * 16 + c0;
        v[e] = (short)f2bf(scale * src[(size_t)k * 128 + col]);
    }
    *reinterpret_cast<bf16x8*>(ws + dst + (size_t)l * 16) = v;
}

// ---------------------------------------------------------------------------
// Main kernel: 256 blocks x 1024 threads (16 waves).  Block = batch.
// Wave w: role = w>>3 (0: layer-0, 1: layer-1 + embedding), t = w&7.
// ---------------------------------------------------------------------------
__global__ __launch_bounds__(1024)
__attribute__((amdgpu_num_vgpr(128)))
void tree_enc(
        const float* __restrict__ X,       // [131072][64]
        const float* __restrict__ emb_b,   // [128]
        const char*  __restrict__ frags,   // ws
        float* __restrict__ out) {         // [256][128]

    __shared__ __align__(16) unsigned short h0b[2][32][136];    // 17408 B
    __shared__ __align__(16) unsigned short h1b[2][32][136];    // 17408 B

    const int tid  = threadIdx.x;
    const int w    = tid >> 6;
    const int l    = tid & 63;
    const int g    = l >> 4;
    const int c0   = l & 15;
    const int b    = blockIdx.x;
    const int role = w >> 3;              // 0 = layer-0 wave, 1 = layer-1 wave
    const int t    = w & 7;
    const int ct   = t * 16 + c0;         // this wave's output column

    const float* biasf = reinterpret_cast<const float*>(frags + 212992);
    const float Bi = biasf[role * 384 + ct];
    const float Bo = biasf[role * 384 + 128 + ct];
    const float Bc = biasf[role * 384 + 256 + ct];

    // persistent B-fragments for this wave's (layer, t) slice: 48 VGPRs
    bf16x8 BUF[12];
    {
        const char* fb = frags + 16384 +
                         (size_t)((role * 8 + t) * 12) * 1024 + (size_t)l * 16;
#pragma unroll
        for (int i = 0; i < 12; ++i)
            BUF[i] = *reinterpret_cast<const bf16x8*>(fb + (size_t)i * 1024);
    }

    // embedding fragments + bias (layer-1 waves only)
    bf16x8 EMB0, EMB1;
    float  be = 0.0f;
    if (role == 1) {
        const char* eb = frags + (size_t)(t * 2) * 1024 + (size_t)l * 16;
        EMB0 = *reinterpret_cast<const bf16x8*>(eb);
        EMB1 = *reinterpret_cast<const bf16x8*>(eb + 1024);
        be   = emb_b[ct];
    }

    float msum = 0.0f;

    // -------- prologue: layer-1 waves embed tile 0 into h0b[0] --------
    if (role == 1) {
#pragma unroll
        for (int mi = 0; mi < 2; ++mi) {
            const float* xr = X + (size_t)(b * 512 + mi * 16 + c0) * 64;
            float4 v0 = *reinterpret_cast<const float4*>(xr + g * 8);
            float4 v1 = *reinterpret_cast<const float4*>(xr + g * 8 + 4);
            float4 v2 = *reinterpret_cast<const float4*>(xr + 32 + g * 8);
            float4 v3 = *reinterpret_cast<const float4*>(xr + 32 + g * 8 + 4);
            bf16x8 a0 = pack8(v0, v1);
            bf16x8 a1 = pack8(v2, v3);
            f32x4 acc = {be, be, be, be};
            acc = MFMA16(a0, EMB0, acc);
            acc = MFMA16(a1, EMB1, acc);
#pragma unroll
            for (int r = 0; r < 4; ++r)
                h0b[0][mi * 16 + g * 4 + r][ct] = f2bf(acc[r]);
        }
    }
    __syncthreads();

    // -------- 17 beats --------
    for (int j = 0; j <= 16; ++j) {
        if (role == 0) {
            // layer-0: tile j from h0b[j&1] -> h1b[j&1]
            if (j < 16) {
                const unsigned short (*src)[136] = h0b[j & 1];
                unsigned short (*dst)[136]       = h1b[j & 1];
#pragma unroll
                for (int mi = 0; mi < 2; ++mi) {
                    bf16x8 A[4];
#pragma unroll
                    for (int kk = 0; kk < 4; ++kk)
                        A[kk] = *reinterpret_cast<const bf16x8*>(
                                &src[mi * 16 + c0][kk * 32 + g * 8]);
                    f32x4 ai = {Bi, Bi, Bi, Bi};
                    f32x4 ao = {Bo, Bo, Bo, Bo};
                    f32x4 ac = {Bc, Bc, Bc, Bc};
#pragma unroll
                    for (int kk = 0; kk < 4; ++kk) {
                        ac = MFMA16(A[kk], BUF[8 + kk], ac);
                        ai = MFMA16(A[kk], BUF[kk],     ai);
                        ao = MFMA16(A[kk], BUF[4 + kk], ao);
                    }
#pragma unroll
                    for (int r = 0; r < 4; ++r)
                        dst[mi * 16 + g * 4 + r][ct] = f2bf(act_h(ai[r], ao[r], ac[r]));
                }
            }
        } else {
            // layer-1 wave: compute tile j-1; embed tile j+1 (mi-split X prefetch)
            const unsigned short (*src)[136] = h1b[(j - 1) & 1];
            unsigned short (*hd)[136]        = h0b[(j + 1) & 1];
            const int erow = b * 512 + (j + 1) * 32;

            float4 v0, v1, v2, v3;
            if (j < 15) {     // X loads for embedding, mi = 0
                const float* xr = X + (size_t)(erow + c0) * 64;
                v0 = *reinterpret_cast<const float4*>(xr + g * 8);
                v1 = *reinterpret_cast<const float4*>(xr + g * 8 + 4);
                v2 = *reinterpret_cast<const float4*>(xr + 32 + g * 8);
                v3 = *reinterpret_cast<const float4*>(xr + 32 + g * 8 + 4);
            }
            if (j >= 1) {     // layer-1 compute, mi = 0
                bf16x8 A[4];
#pragma unroll
                for (int kk = 0; kk < 4; ++kk)
                    A[kk] = *reinterpret_cast<const bf16x8*>(
                            &src[c0][kk * 32 + g * 8]);
                f32x4 ai = {Bi, Bi, Bi, Bi};
                f32x4 ao = {Bo, Bo, Bo, Bo};
                f32x4 ac = {Bc, Bc, Bc, Bc};
#pragma unroll
                for (int kk = 0; kk < 4; ++kk) {
                    ac = MFMA16(A[kk], BUF[8 + kk], ac);
                    ai = MFMA16(A[kk], BUF[kk],     ai);
                    ao = MFMA16(A[kk], BUF[4 + kk], ao);
                }
#pragma unroll
                for (int r = 0; r < 4; ++r)
                    msum += act_h(ai[r], ao[r], ac[r]);
            }
            float4 u0, u1, u2, u3;
            if (j < 15) {     // embed mi = 0; issue X loads for mi = 1
                bf16x8 a0 = pack8(v0, v1);
                bf16x8 a1 = pack8(v2, v3);
                f32x4 acc = {be, be, be, be};
                acc = MFMA16(a0, EMB0, acc);
                acc = MFMA16(a1, EMB1, acc);
#pragma unroll
                for (int r = 0; r < 4; ++r)
                    hd[g * 4 + r][ct] = f2bf(acc[r]);
                const float* xr = X + (size_t)(erow + 16 + c0) * 64;
                u0 = *reinterpret_cast<const float4*>(xr + g * 8);
                u1 = *reinterpret_cast<const float4*>(xr + g * 8 + 4);
                u2 = *reinterpret_cast<const float4*>(xr + 32 + g * 8);
                u3 = *reinterpret_cast<const float4*>(xr + 32 + g * 8 + 4);
            }
            if (j >= 1) {     // layer-1 compute, mi = 1
                bf16x8 A[4];
#pragma unroll
                for (int kk = 0; kk < 4; ++kk)
                    A[kk] = *reinterpret_cast<const bf16x8*>(
                            &src[16 + c0][kk * 32 + g * 8]);
                f32x4 ai = {Bi, Bi, Bi, Bi};
                f32x4 ao = {Bo, Bo, Bo, Bo};
                f32x4 ac = {Bc, Bc, Bc, Bc};
#pragma unroll
                for (int kk = 0; kk < 4; ++kk) {
                    ac = MFMA16(A[kk], BUF[8 + kk], ac);
                    ai = MFMA16(A[kk], BUF[kk],     ai);
                    ao = MFMA16(A[kk], BUF[4 + kk], ao);
                }
#pragma unroll
                for (int r = 0; r < 4; ++r)
                    msum += act_h(ai[r], ao[r], ac[r]);
            }
            if (j < 15) {     // embed mi = 1
                bf16x8 a0 = pack8(u0, u1);
                bf16x8 a1 = pack8(u2, u3);
                f32x4 acc = {be, be, be, be};
                acc = MFMA16(a0, EMB0, acc);
                acc = MFMA16(a1, EMB1, acc);
#pragma unroll
                for (int r = 0; r < 4; ++r)
                    hd[16 + g * 4 + r][ct] = f2bf(acc[r]);
            }
        }
        __syncthreads();
    }

    // -------- mean over nodes: layer-1 waves own the output --------
    if (role == 1) {
        float v = msum;
        v += __shfl_xor(v, 16);
        v += __shfl_xor(v, 32);
        if (g == 0)
            out[b * 128 + ct] = v * (1.0f / 512.0f);
    }
}

// ---------------------------------------------------------------------------
extern "C" void kernel_launch(void* const* d_in, const int* in_sizes, int n_in,
                              void* d_out, int out_size, void* d_ws, size_t ws_size,
                              hipStream_t stream) {
    const float* X    = (const float*)d_in[0];
    const float* embW = (const float*)d_in[1];
    const float* embb = (const float*)d_in[2];
    const float* Wi   = (const float*)d_in[3];
    const float* Wo   = (const float*)d_in[4];
    const float* Wc   = (const float*)d_in[5];
    const float* bWi  = (const float*)d_in[6];
    const float* bUi  = (const float*)d_in[7];
    const float* bWo  = (const float*)d_in[8];
    const float* bUo  = (const float*)d_in[9];
    const float* bWc  = (const float*)d_in[10];
    const float* bUc  = (const float*)d_in[11];
    float* out = (float*)d_out;
    char*  ws  = (char*)d_ws;

    prep_frags<<<209, 64, 0, stream>>>(embW, Wi, Wo, Wc,
                                       bWi, bUi, bWo, bUo, bWc, bUc, ws);
    tree_enc<<<256, 1024, 0, stream>>>(X, embb, (const char*)ws, out);
}

// Round 14
// 85.147 us; speedup vs baseline: 1.0036x; 1.0036x over previous
//
#include <hip/hip_runtime.h>

// ---------------------------------------------------------------------------
// TreeEncoder fused MFMA kernel, round 14 = round 12/13 with the allocator
// target fixed via amdgpu_waves_per_eu(4,4).
//   r12 (launch_bounds only) and r13 (+amdgpu_num_vgpr(128)) both compiled to
//   VGPR=64: the backend's greedy heuristic targets 8 waves/EU for 1024-thread
//   blocks and num_vgpr is advisory.  waves_per_eu(4,4) sets an occupancy
//   MAXIMUM of 4 waves/EU -> register budget 512/4 = 128, which the design
//   needs (persistent 48-VGPR B-fragment buffer per wave).
//   Design recap (unchanged):
//   - grid 256 x 1024 (1 block/CU, block == batch; no atomics, no memset).
//   - wave w permanently holds the 12 B-fragments of (layer=w>>3, t=w&7).
//   - rows stream in 16 tiles of 32; beat j: L0-waves h0(j)->h1(j);
//     L1-waves h1(j-1)->msum and embed tile j+1.  Double-buffered LDS,
//     ONE __syncthreads per beat, 17 beats.
// ---------------------------------------------------------------------------

typedef short bf16x8 __attribute__((ext_vector_type(8)));
typedef float f32x4  __attribute__((ext_vector_type(4)));

#define MFMA16(a, b, c) __builtin_amdgcn_mfma_f32_16x16x32_bf16((a), (b), (c), 0, 0, 0)

#define NEG_L2E (-1.44269504088896f)
#define TWO_L2E (2.88539008177793f)

__device__ __forceinline__ unsigned short f2bf(float f) {
    return (unsigned short)((__float_as_uint(f) + 0x8000u) >> 16);
}
__device__ __forceinline__ float frcp(float x)  { return __builtin_amdgcn_rcpf(x); }
__device__ __forceinline__ float fexp2(float x) { return __builtin_amdgcn_exp2f(x); }

// scalar Pade[3/2] merged activation: inputs are pre-scaled logits
__device__ __forceinline__ float act_h(float iv, float ov, float cv) {
    float ei = fexp2(iv);
    float eo = fexp2(ov);
    float u  = fexp2(cv);
    float p  = u - 1.0f;
    float q  = (1.0f + ei) * (u + 1.0f);     // cc = p/q = sig(i)*tanh(c~)
    float p2 = p * p, q2 = q * q;
    float t15 = 15.0f * q2;
    return (p * (t15 + p2)) * frcp((q * (6.0f * p2 + t15)) * (1.0f + eo));
}

__device__ __forceinline__ bf16x8 pack8(float4 v0, float4 v1) {
    bf16x8 a;
    a[0] = (short)f2bf(v0.x); a[1] = (short)f2bf(v0.y);
    a[2] = (short)f2bf(v0.z); a[3] = (short)f2bf(v0.w);
    a[4] = (short)f2bf(v1.x); a[5] = (short)f2bf(v1.y);
    a[6] = (short)f2bf(v1.z); a[7] = (short)f2bf(v1.w);
    return a;
}

// ---------------------------------------------------------------------------
// Prep: weights -> MFMA B-fragment bf16 layout in ws, with exp2 prescale;
// plus combined scaled biases.  (identical to rounds 8-13)
// ---------------------------------------------------------------------------
__global__ void prep_frags(const float* __restrict__ embW,
                           const float* __restrict__ Wi,
                           const float* __restrict__ Wo,
                           const float* __restrict__ Wc,
                           const float* __restrict__ bWi, const float* __restrict__ bUi,
                           const float* __restrict__ bWo, const float* __restrict__ bUo,
                           const float* __restrict__ bWc, const float* __restrict__ bUc,
                           char* __restrict__ ws) {
    int fb = blockIdx.x;          // 0..208
    int l  = threadIdx.x;         // 0..63

    if (fb == 208) {              // combined scaled biases: [layer][gate][128]
        float* bias = reinterpret_cast<float*>(ws + 212992);
#pragma unroll
        for (int j = 0; j < 12; ++j) {
            int v = j * 64 + l;                 // 0..767
            int layer = v / 384;
            int r = v % 384;
            int gate = r >> 7;
            int c = r & 127;
            int idx = layer * 128 + c;
            float x;
            if (gate == 0)      x = NEG_L2E * (bWi[idx] + bUi[idx]);
            else if (gate == 1) x = NEG_L2E * (bWo[idx] + bUo[idx]);
            else                x = TWO_L2E * (bWc[idx] + bUc[idx]);
            bias[v] = x;
        }
        return;
    }

    int g  = l >> 4, c0 = l & 15;
    const float* src;
    int t, kk;
    size_t dst;
    float scale;
    if (fb < 16) {
        t = fb >> 1; kk = fb & 1;
        src = embW;                                   // [64][128]
        dst = (size_t)fb * 1024;
        scale = 1.0f;
    } else {
        int r = fb - 16;                              // (layer*8+t)*12+gate*4+kk
        int layer = r / 96;
        int r2 = r % 96;
        t = r2 / 12;
        int r3 = r2 % 12;
        int gate = r3 >> 2;
        kk = r3 & 3;
        const float* Ws[3] = {Wi, Wo, Wc};
        src = Ws[gate] + (size_t)layer * 128 * 128;   // [128][128]
        dst = 16384 + (size_t)r * 1024;
        scale = (gate == 2) ? TWO_L2E : NEG_L2E;
    }

    bf16x8 v;
#pragma unroll
    for (int e = 0; e < 8; ++e) {
        int k   = kk * 32 + g * 8 + e;
        int col = t * 16 + c0;
        v[e] = (short)f2bf(scale * src[(size_t)k * 128 + col]);
    }
    *reinterpret_cast<bf16x8*>(ws + dst + (size_t)l * 16) = v;
}

// ---------------------------------------------------------------------------
// Main kernel: 256 blocks x 1024 threads (16 waves).  Block = batch.
// Wave w: role = w>>3 (0: layer-0, 1: layer-1 + embedding), t = w&7.
// ---------------------------------------------------------------------------
__global__ __launch_bounds__(1024)
__attribute__((amdgpu_waves_per_eu(4, 4)))
void tree_enc(
        const float* __restrict__ X,       // [131072][64]
        const float* __restrict__ emb_b,   // [128]
        const char*  __restrict__ frags,   // ws
        float* __restrict__ out) {         // [256][128]

    __shared__ __align__(16) unsigned short h0b[2][32][136];    // 17408 B
    __shared__ __align__(16) unsigned short h1b[2][32][136];    // 17408 B

    const int tid  = threadIdx.x;
    const int w    = tid >> 6;
    const int l    = tid & 63;
    const int g    = l >> 4;
    const int c0   = l & 15;
    const int b    = blockIdx.x;
    const int role = w >> 3;              // 0 = layer-0 wave, 1 = layer-1 wave
    const int t    = w & 7;
    const int ct   = t * 16 + c0;         // this wave's output column

    const float* biasf = reinterpret_cast<const float*>(frags + 212992);
    const float Bi = biasf[role * 384 + ct];
    const float Bo = biasf[role * 384 + 128 + ct];
    const float Bc = biasf[role * 384 + 256 + ct];

    // persistent B-fragments for this wave's (layer, t) slice: 48 VGPRs
    bf16x8 BUF[12];
    {
        const char* fb = frags + 16384 +
                         (size_t)((role * 8 + t) * 12) * 1024 + (size_t)l * 16;
#pragma unroll
        for (int i = 0; i < 12; ++i)
            BUF[i] = *reinterpret_cast<const bf16x8*>(fb + (size_t)i * 1024);
    }

    // embedding fragments + bias (layer-1 waves only)
    bf16x8 EMB0, EMB1;
    float  be = 0.0f;
    if (role == 1) {
        const char* eb = frags + (size_t)(t * 2) * 1024 + (size_t)l * 16;
        EMB0 = *reinterpret_cast<const bf16x8*>(eb);
        EMB1 = *reinterpret_cast<const bf16x8*>(eb + 1024);
        be   = emb_b[ct];
    }

    float msum = 0.0f;

    // -------- prologue: layer-1 waves embed tile 0 into h0b[0] --------
    if (role == 1) {
#pragma unroll
        for (int mi = 0; mi < 2; ++mi) {
            const float* xr = X + (size_t)(b * 512 + mi * 16 + c0) * 64;
            float4 v0 = *reinterpret_cast<const float4*>(xr + g * 8);
            float4 v1 = *reinterpret_cast<const float4*>(xr + g * 8 + 4);
            float4 v2 = *reinterpret_cast<const float4*>(xr + 32 + g * 8);
            float4 v3 = *reinterpret_cast<const float4*>(xr + 32 + g * 8 + 4);
            bf16x8 a0 = pack8(v0, v1);
            bf16x8 a1 = pack8(v2, v3);
            f32x4 acc = {be, be, be, be};
            acc = MFMA16(a0, EMB0, acc);
            acc = MFMA16(a1, EMB1, acc);
#pragma unroll
            for (int r = 0; r < 4; ++r)
                h0b[0][mi * 16 + g * 4 + r][ct] = f2bf(acc[r]);
        }
    }
    __syncthreads();

    // -------- 17 beats --------
    for (int j = 0; j <= 16; ++j) {
        if (role == 0) {
            // layer-0: tile j from h0b[j&1] -> h1b[j&1]
            if (j < 16) {
                const unsigned short (*src)[136] = h0b[j & 1];
                unsigned short (*dst)[136]       = h1b[j & 1];
#pragma unroll
                for (int mi = 0; mi < 2; ++mi) {
                    bf16x8 A[4];
#pragma unroll
                    for (int kk = 0; kk < 4; ++kk)
                        A[kk] = *reinterpret_cast<const bf16x8*>(
                                &src[mi * 16 + c0][kk * 32 + g * 8]);
                    f32x4 ai = {Bi, Bi, Bi, Bi};
                    f32x4 ao = {Bo, Bo, Bo, Bo};
                    f32x4 ac = {Bc, Bc, Bc, Bc};
#pragma unroll
                    for (int kk = 0; kk < 4; ++kk) {
                        ac = MFMA16(A[kk], BUF[8 + kk], ac);
                        ai = MFMA16(A[kk], BUF[kk],     ai);
                        ao = MFMA16(A[kk], BUF[4 + kk], ao);
                    }
#pragma unroll
                    for (int r = 0; r < 4; ++r)
                        dst[mi * 16 + g * 4 + r][ct] = f2bf(act_h(ai[r], ao[r], ac[r]));
                }
            }
        } else {
            // layer-1 wave: compute tile j-1; embed tile j+1 (mi-split X prefetch)
            const unsigned short (*src)[136] = h1b[(j - 1) & 1];
            unsigned short (*hd)[136]        = h0b[(j + 1) & 1];
            const int erow = b * 512 + (j + 1) * 32;

            float4 v0, v1, v2, v3;
            if (j < 15) {     // X loads for embedding, mi = 0
                const float* xr = X + (size_t)(erow + c0) * 64;
                v0 = *reinterpret_cast<const float4*>(xr + g * 8);
                v1 = *reinterpret_cast<const float4*>(xr + g * 8 + 4);
                v2 = *reinterpret_cast<const float4*>(xr + 32 + g * 8);
                v3 = *reinterpret_cast<const float4*>(xr + 32 + g * 8 + 4);
            }
            if (j >= 1) {     // layer-1 compute, mi = 0
                bf16x8 A[4];
#pragma unroll
                for (int kk = 0; kk < 4; ++kk)
                    A[kk] = *reinterpret_cast<const bf16x8*>(
                            &src[c0][kk * 32 + g * 8]);
                f32x4 ai = {Bi, Bi, Bi, Bi};
                f32x4 ao = {Bo, Bo, Bo, Bo};
                f32x4 ac = {Bc, Bc, Bc, Bc};
#pragma unroll
                for (int kk = 0; kk < 4; ++kk) {
                    ac = MFMA16(A[kk], BUF[8 + kk], ac);
                    ai = MFMA16(A[kk], BUF[kk],     ai);
                    ao = MFMA16(A[kk], BUF[4 + kk], ao);
                }
#pragma unroll
                for (int r = 0; r < 4; ++r)
                    msum += act_h(ai[r], ao[r], ac[r]);
            }
            float4 u0, u1, u2, u3;
            if (j < 15) {     // embed mi = 0; issue X loads for mi = 1
                bf16x8 a0 = pack8(v0, v1);
                bf16x8 a1 = pack8(v2, v3);
                f32x4 acc = {be, be, be, be};
                acc = MFMA16(a0, EMB0, acc);
                acc = MFMA16(a1, EMB1, acc);
#pragma unroll
                for (int r = 0; r < 4; ++r)
                    hd[g * 4 + r][ct] = f2bf(acc[r]);
                const float* xr = X + (size_t)(erow + 16 + c0) * 64;
                u0 = *reinterpret_cast<const float4*>(xr + g * 8);
                u1 = *reinterpret_cast<const float4*>(xr + g * 8 + 4);
                u2 = *reinterpret_cast<const float4*>(xr + 32 + g * 8);
                u3 = *reinterpret_cast<const float4*>(xr + 32 + g * 8 + 4);
            }
            if (j >= 1) {     // layer-1 compute, mi = 1
                bf16x8 A[4];
#pragma unroll
                for (int kk = 0; kk < 4; ++kk)
                    A[kk] = *reinterpret_cast<const bf16x8*>(
                            &src[16 + c0][kk * 32 + g * 8]);
                f32x4 ai = {Bi, Bi, Bi, Bi};
                f32x4 ao = {Bo, Bo, Bo, Bo};
                f32x4 ac = {Bc, Bc, Bc, Bc};
#pragma unroll
                for (int kk = 0; kk < 4; ++kk) {
                    ac = MFMA16(A[kk], BUF[8 + kk], ac);
                    ai = MFMA16(A[kk], BUF[kk],     ai);
                    ao = MFMA16(A[kk], BUF[4 + kk], ao);
                }
#pragma unroll
                for (int r = 0; r < 4; ++r)
                    msum += act_h(ai[r], ao[r], ac[r]);
            }
            if (j < 15) {     // embed mi = 1
                bf16x8 a0 = pack8(u0, u1);
                bf16x8 a1 = pack8(u2, u3);
                f32x4 acc = {be, be, be, be};
                acc = MFMA16(a0, EMB0, acc);
                acc = MFMA16(a1, EMB1, acc);
#pragma unroll
                for (int r = 0; r < 4; ++r)
                    hd[16 + g * 4 + r][ct] = f2bf(acc[r]);
            }
        }
        __syncthreads();
    }

    // -------- mean over nodes: layer-1 waves own the output --------
    if (role == 1) {
        float v = msum;
        v += __shfl_xor(v, 16);
        v += __shfl_xor(v, 32);
        if (g == 0)
            out[b * 128 + ct] = v * (1.0f / 512.0f);
    }
}

// ---------------------------------------------------------------------------
extern "C" void kernel_launch(void* const* d_in, const int* in_sizes, int n_in,
                              void* d_out, int out_size, void* d_ws, size_t ws_size,
                              hipStream_t stream) {
    const float* X    = (const float*)d_in[0];
    const float* embW = (const float*)d_in[1];
    const float* embb = (const float*)d_in[2];
    const float* Wi   = (const float*)d_in[3];
    const float* Wo   = (const float*)d_in[4];
    const float* Wc   = (const float*)d_in[5];
    const float* bWi  = (const float*)d_in[6];
    const float* bUi  = (const float*)d_in[7];
    const float* bWo  = (const float*)d_in[8];
    const float* bUo  = (const float*)d_in[9];
    const float* bWc  = (const float*)d_in[10];
    const float* bUc  = (const float*)d_in[11];
    float* out = (float*)d_out;
    char*  ws  = (char*)d_ws;

    prep_frags<<<209, 64, 0, stream>>>(embW, Wi, Wo, Wc,
                                       bWi, bUi, bWo, bUo, bWc, bUc, ws);
    tree_enc<<<256, 1024, 0, stream>>>(X, embb, (const char*)ws, out);
}